// Round 10
// baseline (259.894 us; speedup 1.0000x reference)
//
#include <hip/hip_runtime.h>
#include <math.h>

#define EPS_ 1e-8f
#define LAM_ 1e-3f

// ---------------- K1: 5x5 conv s2 p2 + BN + ReLU, fused with weight transposes ----------------
__global__ __launch_bounds__(256) void k_conv_transw(
    const float* __restrict__ x, const float* __restrict__ cw, const float* __restrict__ cb,
    const float* __restrict__ g, const float* __restrict__ bb,
    const float* __restrict__ mean, const float* __restrict__ var,
    float* __restrict__ y,
    const float* __restrict__ w1, const float* __restrict__ w2, const float* __restrict__ wc,
    const float* __restrict__ pw, const float* __restrict__ pb,
    const float* __restrict__ aw, const float* __restrict__ ab,
    float* __restrict__ w1t, float* __restrict__ w2t, float* __restrict__ wct,
    float* __restrict__ wpt)
{
    if (blockIdx.x < 4096) {
        int t = blockIdx.x * 256 + threadIdx.x;          // < 64*16*16*64
        int ch = t & 63, w = (t >> 6) & 15, h = (t >> 10) & 15, b = t >> 14;
        const float* xb = x + b * 1024;
        const float* wc_ = cw + ch * 25;
        float acc = cb[ch];
        #pragma unroll
        for (int kh = 0; kh < 5; ++kh) {
            int ih = h * 2 - 2 + kh;
            if (ih < 0 || ih > 31) continue;
            #pragma unroll
            for (int kw = 0; kw < 5; ++kw) {
                int iw = w * 2 - 2 + kw;
                if (iw < 0 || iw > 31) continue;
                acc = fmaf(xb[ih * 32 + iw], wc_[kh * 5 + kw], acc);
            }
        }
        float v = (acc - mean[ch]) * (g[ch] * rsqrtf(var[ch] + 1e-3f)) + bb[ch];
        y[t] = fmaxf(v, 0.f);
    } else {
        int t = (blockIdx.x - 4096) * 256 + threadIdx.x;
        if (t < 3616 * 16) {
            int m = t >> 4, e = t & 15, r = e >> 2, q = e & 3;
            const float* src; float* dst;
            if (m < 1152)      { src = w1 + m * 16;          dst = w1t + m * 16; }
            else if (m < 3456) { src = w2 + (m - 1152) * 16; dst = w2t + (m - 1152) * 16; }
            else               { src = wc + (m - 3456) * 16; dst = wct + (m - 3456) * 16; }
            dst[e] = src[q * 4 + r];
        } else if (t < 3616 * 16 + 65 * 136) {
            int idx = t - 3616 * 16;
            int o = idx % 136, j = idx / 136;
            float v;
            if (j == 64)       v = (o < 128) ? pb[o] : ab[o - 128];
            else if (o < 128)  v = pw[o * 64 + j];
            else               v = aw[(o - 128) * 64 + j];
            wpt[j * 136 + o] = v;
        }
    }
}

// ---------------- K2: primary caps (coalesced GEMM) ----------------
__global__ __launch_bounds__(256) void k_prim(
    const float* __restrict__ y, const float* __restrict__ wpt,
    float* __restrict__ poseP, float* __restrict__ aP)
{
    int t = blockIdx.x * 256 + threadIdx.x;
    if (t >= 16384 * 34) return;
    int oq = t % 34;
    int pos = t / 34;
    const float* yp = y + pos * 64;
    float4 acc = *(const float4*)(wpt + 64 * 136 + oq * 4);   // bias row
    #pragma unroll
    for (int j0 = 0; j0 < 64; j0 += 4) {
        float4 y4 = *(const float4*)(yp + j0);
        float4 w0 = *(const float4*)(wpt + (j0 + 0) * 136 + oq * 4);
        float4 w1 = *(const float4*)(wpt + (j0 + 1) * 136 + oq * 4);
        float4 w2 = *(const float4*)(wpt + (j0 + 2) * 136 + oq * 4);
        float4 w3 = *(const float4*)(wpt + (j0 + 3) * 136 + oq * 4);
        acc.x = fmaf(y4.x, w0.x, fmaf(y4.y, w1.x, fmaf(y4.z, w2.x, fmaf(y4.w, w3.x, acc.x))));
        acc.y = fmaf(y4.x, w0.y, fmaf(y4.y, w1.y, fmaf(y4.z, w2.y, fmaf(y4.w, w3.y, acc.y))));
        acc.z = fmaf(y4.x, w0.z, fmaf(y4.y, w1.z, fmaf(y4.z, w2.z, fmaf(y4.w, w3.z, acc.z))));
        acc.w = fmaf(y4.x, w0.w, fmaf(y4.y, w1.w, fmaf(y4.z, w2.w, fmaf(y4.w, w3.w, acc.w))));
    }
    if (oq < 32) {
        ((float4*)(poseP + pos * 128))[oq] = acc;
    } else {
        int oo = (oq - 32) * 4;
        float* ad = aP + pos * 8 + oo;
        ad[0] = 1.f / (1.f + __expf(-acc.x));
        ad[1] = 1.f / (1.f + __expf(-acc.y));
        ad[2] = 1.f / (1.f + __expf(-acc.z));
        ad[3] = 1.f / (1.f + __expf(-acc.w));
    }
}

// ---------------- single-wave capsule routing (stages 1 & 2) ----------------
// One position per 64-thread block. LDS = pp+ap only (~5-10 KB) to maximize
// block residency. Lane=(ig=lane>>4, cc=lane&15). Pass B pairs two i-iterations
// so two independent shuffle chains interleave their waits.
template<int N, int C, int K, int S, int H, int W, int Bi, int OH, int OW>
__global__ __launch_bounds__(64) void k_caps_w1(
    const float* __restrict__ pose_in,  // (b,H,W,Bi,16)
    const float* __restrict__ a_in,     // (b,H,W,Bi)
    const float* __restrict__ Wt,       // (N,C,16) r-major transposed
    const float* __restrict__ bu, const float* __restrict__ ba,
    float* __restrict__ pose_out,       // (b,OH,OW,C,16)
    float* __restrict__ a_out)          // (b,OH,OW,C)
{
    static_assert(C == 16 && N % 8 == 0, "");
    constexpr int NIT = N / 4;
    constexpr int NP  = NIT / 2;

    __shared__ __align__(16) float pp[N * 16];
    __shared__ float ap[N];

    const int lane = threadIdx.x;
    const int n_ = blockIdx.x;
    const int b = n_ / (OH * OW);
    const int rem = n_ % (OH * OW);
    const int oh = rem / OW, ow = rem % OW;

    // ---- gather patch pose (float4) + activation into LDS ----
    for (int idx = lane; idx < N * 4; idx += 64) {
        int i = idx >> 2, f = idx & 3;
        int bi = i % Bi, k2 = i / Bi;
        int sw = ow * S + (k2 % K), sh = oh * S + (k2 / K);
        ((float4*)(pp + i * 16))[f] =
            ((const float4*)(pose_in + (((b * H + sh) * W + sw) * Bi + bi) * 16))[f];
    }
    for (int i = lane; i < N; i += 64) {
        int bi = i % Bi, k2 = i / Bi;
        int sw = ow * S + (k2 % K), sh = oh * S + (k2 / K);
        ap[i] = a_in[((b * H + sh) * W + sw) * Bi + bi];
    }
    __syncthreads();

    // ---- inv0 = 1/(sum a + C^2*EPS) ----
    float suma = 0.f;
    for (int i = lane; i < N; i += 64) suma += ap[i];
    #pragma unroll
    for (int m = 1; m < 64; m <<= 1) suma += __shfl_xor(suma, m, 64);
    const float inv0 = __builtin_amdgcn_rcpf(suma + (float)(C * C) * EPS_);

    const int ig = (lane >> 4) & 3, cc = lane & 15;

    // ================= pass A: mu0 =================
    float mu[16];
    #pragma unroll
    for (int e2 = 0; e2 < 16; ++e2) mu[e2] = 0.f;
    for (int ii = 0; ii < NIT; ++ii) {
        int i = ig + ii * 4;
        const float4* pi4 = (const float4*)(pp + i * 16);
        const float4* wt4 = (const float4*)(Wt + (i * C + cc) * 16);
        float4 pv[4] = { pi4[0], pi4[1], pi4[2], pi4[3] };
        float4 wv[4] = { wt4[0], wt4[1], wt4[2], wt4[3] };
        float co = ap[i] * inv0;
        #pragma unroll
        for (int e2 = 0; e2 < 16; ++e2) {
            float4 p4 = pv[e2 >> 2], w4 = wv[e2 & 3];
            float v = p4.x * w4.x + p4.y * w4.y + p4.z * w4.z + p4.w * w4.w;
            mu[e2] = fmaf(co, v, mu[e2]);
        }
    }
    #pragma unroll
    for (int e2 = 0; e2 < 16; ++e2) {
        mu[e2] += __shfl_xor(mu[e2], 16, 64);
        mu[e2] += __shfl_xor(mu[e2], 32, 64);   // every lane: mu0[cc][e2]
    }

    // ================= pass B: paired i-iterations =================
    float Sv[16], Sv2[16];
    #pragma unroll
    for (int e2 = 0; e2 < 16; ++e2) { Sv[e2] = 0.f; Sv2[e2] = 0.f; }
    float rsum = 0.f;
    for (int jj = 0; jj < NP; ++jj) {
        int i0 = ig + (2 * jj) * 4;
        int i1 = i0 + 4;
        const float4* p04 = (const float4*)(pp + i0 * 16);
        const float4* w04 = (const float4*)(Wt + (i0 * C + cc) * 16);
        const float4* p14 = (const float4*)(pp + i1 * 16);
        const float4* w14 = (const float4*)(Wt + (i1 * C + cc) * 16);
        float4 pv0[4] = { p04[0], p04[1], p04[2], p04[3] };
        float4 wv0[4] = { w04[0], w04[1], w04[2], w04[3] };
        float4 pv1[4] = { p14[0], p14[1], p14[2], p14[3] };
        float4 wv1[4] = { w14[0], w14[1], w14[2], w14[3] };
        float vv0[16], vv1[16];
        float d0 = EPS_, d1 = EPS_;
        #pragma unroll
        for (int e2 = 0; e2 < 16; ++e2) {
            float4 a4 = pv0[e2 >> 2], x4 = wv0[e2 & 3];
            float4 b4 = pv1[e2 >> 2], y4 = wv1[e2 & 3];
            float v0 = a4.x * x4.x + a4.y * x4.y + a4.z * x4.z + a4.w * x4.w;
            float v1 = b4.x * y4.x + b4.y * y4.y + b4.z * y4.z + b4.w * y4.w;
            vv0[e2] = v0; vv1[e2] = v1;
            float e0 = v0 - mu[e2];
            float e1 = v1 - mu[e2];
            d0 = fmaf(e0, e0, d0);
            d1 = fmaf(e1, e1, d1);
        }
        float inv_0 = __builtin_amdgcn_rcpf(d0);
        float inv_1 = __builtin_amdgcn_rcpf(d1);
        float s0 = inv_0, s1 = inv_1;
        #pragma unroll
        for (int m = 1; m < 16; m <<= 1) {
            s0 += __shfl_xor(s0, m, 64);
            s1 += __shfl_xor(s1, m, 64);
        }
        float r10 = inv_0 * __builtin_amdgcn_rcpf(s0 + EPS_);
        float r11 = inv_1 * __builtin_amdgcn_rcpf(s1 + EPS_);
        float rm0 = r10 * r10 * ap[i0];
        float rm1 = r11 * r11 * ap[i1];
        rsum += rm0 + rm1;
        #pragma unroll
        for (int e2 = 0; e2 < 16; ++e2) {
            float rv0 = rm0 * vv0[e2];
            float rv1 = rm1 * vv1[e2];
            Sv[e2] += rv0 + rv1;
            Sv2[e2] = fmaf(rv0, vv0[e2], fmaf(rv1, vv1[e2], Sv2[e2]));
        }
    }
    #pragma unroll
    for (int e2 = 0; e2 < 16; ++e2) {
        Sv[e2] += __shfl_xor(Sv[e2], 16, 64);
        Sv[e2] += __shfl_xor(Sv[e2], 32, 64);
        Sv2[e2] += __shfl_xor(Sv2[e2], 16, 64);
        Sv2[e2] += __shfl_xor(Sv2[e2], 32, 64);
    }
    rsum += __shfl_xor(rsum, 16, 64);
    rsum += __shfl_xor(rsum, 32, 64);

    // ================= epilogue (registers; lanes 0-15 store) =================
    const float id = 1.f / (rsum + EPS_);
    const float S0 = rsum * id;
    const float buc_ = bu[cc];
    float cs = 0.f;
    float4 outv[4];
    #pragma unroll
    for (int e2 = 0; e2 < 16; ++e2) {
        float sv = Sv[e2] * id;
        float sv2 = Sv2[e2] * id;
        float sigma = fmaxf(sv2 + sv * sv * (S0 - 2.f), 0.f) + EPS_;
        cs += (buc_ + 0.5f * __logf(sigma)) * rsum;
        ((float*)outv)[e2] = sv;
    }
    if (lane < 16) {
        float4* pd = (float4*)(pose_out + (n_ * C + cc) * 16);
        pd[0] = outv[0]; pd[1] = outv[1]; pd[2] = outv[2]; pd[3] = outv[3];
        a_out[n_ * C + cc] = 1.f / (1.f + __expf(-(LAM_ * (ba[cc] - cs))));
    }
}

// ---------------- block-wide caps (class layer, COORDS) ----------------
template<int N, int C, int H, int W, int Bi, int BLK>
__global__ __launch_bounds__(BLK) void k_caps_class(
    const float* __restrict__ pose_in, const float* __restrict__ a_in,
    const float* __restrict__ Wt,
    const float* __restrict__ bu, const float* __restrict__ ba,
    float* __restrict__ a_out)
{
    constexpr int NW  = BLK / 64;
    constexpr int NIG = BLK / 16;
    constexpr int NIT = (N + NIG - 1) / NIG;

    __shared__ __align__(16) float pp[N * 16];
    __shared__ float ap[N];
    __shared__ float coeff0[N];
    __shared__ float mu0[16 * 17];
    __shared__ float red1[NW * C * 17];
    __shared__ float red2[NW * C * 17];
    __shared__ float redr[NW * C];

    const int t = threadIdx.x;
    const int lane = t & 63;
    const int w = t >> 6;
    const int b = blockIdx.x;

    for (int idx = t; idx < N * 4; idx += BLK) {
        int i = idx >> 2, f = idx & 3;
        int bi = i % Bi;
        int hw = i / Bi;
        int sw = hw % W, sh = hw / W;
        const float4* src = (const float4*)(pose_in + (((b * H + sh) * W + sw) * Bi + bi) * 16);
        ((float4*)(pp + i * 16))[f] = src[f];
    }
    for (int i = t; i < N; i += BLK) {
        int bi = i % Bi;
        int hw = i / Bi;
        int sw = hw % W, sh = hw / W;
        ap[i] = a_in[((b * H + sh) * W + sw) * Bi + bi];
    }
    __syncthreads();

    {
        float part = 0.f;
        for (int i = t; i < N; i += BLK) part += ap[i];
        #pragma unroll
        for (int m = 1; m < 64; m <<= 1) part += __shfl_xor(part, m, 64);
        if (lane == 0) red1[w] = part;
        __syncthreads();
        float s = 0.f;
        #pragma unroll
        for (int ww = 0; ww < NW; ++ww) s += red1[ww];
        float inv0 = __builtin_amdgcn_rcpf(s + (float)(C * C) * EPS_);
        for (int i = t; i < N; i += BLK) coeff0[i] = ap[i] * inv0;
        __syncthreads();
    }

    const int ig = t >> 4, cc = t & 15;

    // pass A
    {
        float muU[16];
        #pragma unroll
        for (int e2 = 0; e2 < 16; ++e2) muU[e2] = 0.f;
        if (cc < C) {
            for (int ii = 0; ii < NIT; ++ii) {
                int i = ig + ii * NIG;
                if (i < N) {
                    const float4* pi4 = (const float4*)(pp + i * 16);
                    const float4* wt4 = (const float4*)(Wt + ((i % Bi) * C + cc) * 16);
                    float4 pv[4] = { pi4[0], pi4[1], pi4[2], pi4[3] };
                    float4 wv[4] = { wt4[0], wt4[1], wt4[2], wt4[3] };
                    float co = coeff0[i];
                    float chv = (float)(i / (W * Bi)) * (1.f / H);
                    float cwv = (float)((i / Bi) % W) * (1.f / W);
                    #pragma unroll
                    for (int e2 = 0; e2 < 16; ++e2) {
                        float4 p4 = pv[e2 >> 2], w4 = wv[e2 & 3];
                        float v = p4.x * w4.x + p4.y * w4.y + p4.z * w4.z + p4.w * w4.w;
                        if (e2 == 0) v += chv;
                        if (e2 == 1) v += cwv;
                        muU[e2] = fmaf(co, v, muU[e2]);
                    }
                }
            }
        }
        #pragma unroll
        for (int e2 = 0; e2 < 16; ++e2) {
            float xv = muU[e2];
            xv += __shfl_xor(xv, 16, 64);
            xv += __shfl_xor(xv, 32, 64);
            if (lane < 16 && lane < C) red1[(w * C + lane) * 17 + e2] = xv;
        }
        __syncthreads();
        if (t < 256) {
            int c = t >> 4, e = t & 15;
            if (c < C) {
                float m = 0.f;
                #pragma unroll
                for (int ww = 0; ww < NW; ++ww) m += red1[(ww * C + c) * 17 + e];
                mu0[c * 17 + e] = m;
            }
        }
        __syncthreads();
    }

    // pass B
    {
        float m0[16];
        if (cc < C) {
            #pragma unroll
            for (int e2 = 0; e2 < 16; ++e2) m0[e2] = mu0[cc * 17 + e2];
        }
        float SvU[16], Sv2U[16];
        #pragma unroll
        for (int e2 = 0; e2 < 16; ++e2) { SvU[e2] = 0.f; Sv2U[e2] = 0.f; }
        float rsumP = 0.f;

        for (int ii = 0; ii < NIT; ++ii) {
            int i = ig + ii * NIG;
            bool act = (i < N);
            float inv = 0.f;
            float vv[16];
            if (act && cc < C) {
                const float4* pi4 = (const float4*)(pp + i * 16);
                const float4* wt4 = (const float4*)(Wt + ((i % Bi) * C + cc) * 16);
                float4 pv[4] = { pi4[0], pi4[1], pi4[2], pi4[3] };
                float4 wv[4] = { wt4[0], wt4[1], wt4[2], wt4[3] };
                float chv = (float)(i / (W * Bi)) * (1.f / H);
                float cwv = (float)((i / Bi) % W) * (1.f / W);
                float dist = EPS_;
                #pragma unroll
                for (int e2 = 0; e2 < 16; ++e2) {
                    float4 p4 = pv[e2 >> 2], w4 = wv[e2 & 3];
                    float v = p4.x * w4.x + p4.y * w4.y + p4.z * w4.z + p4.w * w4.w;
                    if (e2 == 0) v += chv;
                    if (e2 == 1) v += cwv;
                    vv[e2] = v;
                    float d = v - m0[e2];
                    dist = fmaf(d, d, dist);
                }
                inv = __builtin_amdgcn_rcpf(dist);
            }
            float s = inv;
            #pragma unroll
            for (int m = 1; m < 16; m <<= 1) s += __shfl_xor(s, m, 64);
            if (act && cc < C) {
                float r1 = inv * __builtin_amdgcn_rcpf(s + EPS_);
                float rm = r1 * r1 * ap[i];
                rsumP += rm;
                #pragma unroll
                for (int e2 = 0; e2 < 16; ++e2) {
                    SvU[e2] = fmaf(rm, vv[e2], SvU[e2]);
                    Sv2U[e2] = fmaf(rm * vv[e2], vv[e2], Sv2U[e2]);
                }
            }
        }
        #pragma unroll
        for (int e2 = 0; e2 < 16; ++e2) {
            float xv = SvU[e2];
            xv += __shfl_xor(xv, 16, 64);
            xv += __shfl_xor(xv, 32, 64);
            float yv = Sv2U[e2];
            yv += __shfl_xor(yv, 16, 64);
            yv += __shfl_xor(yv, 32, 64);
            if (lane < 16 && lane < C) {
                red1[(w * C + lane) * 17 + e2] = xv;
                red2[(w * C + lane) * 17 + e2] = yv;
            }
        }
        {
            float rv = rsumP;
            rv += __shfl_xor(rv, 16, 64);
            rv += __shfl_xor(rv, 32, 64);
            if (lane < 16 && lane < C) redr[w * C + lane] = rv;
        }
        __syncthreads();
    }

    if (t < 256) {
        int c = t >> 4, e = t & 15;
        if (c < C) {
            float SvT = 0.f, Sv2T = 0.f, R = 0.f;
            #pragma unroll
            for (int ww = 0; ww < NW; ++ww) {
                SvT  += red1[(ww * C + c) * 17 + e];
                Sv2T += red2[(ww * C + c) * 17 + e];
                R    += redr[ww * C + c];
            }
            float id = 1.f / (R + EPS_);
            float S0 = R * id;
            float Sv = SvT * id;
            float Sv2 = Sv2T * id;
            float sigma = fmaxf(Sv2 + Sv * Sv * (S0 - 2.f), 0.f) + EPS_;
            float cost = (bu[c] + 0.5f * __logf(sigma)) * R;
            float cs = cost;
            #pragma unroll
            for (int m = 1; m < 16; m <<= 1) cs += __shfl_xor(cs, m, 64);
            if (e == 0) a_out[b * C + c] = 1.f / (1.f + __expf(-(LAM_ * (ba[c] - cs))));
        }
    }
}

extern "C" void kernel_launch(void* const* d_in, const int* in_sizes, int n_in,
                              void* d_out, int out_size, void* d_ws, size_t ws_size,
                              hipStream_t stream)
{
    const float* x   = (const float*)d_in[0];
    const float* c1w = (const float*)d_in[1];
    const float* c1b = (const float*)d_in[2];
    const float* bng = (const float*)d_in[3];
    const float* bnb = (const float*)d_in[4];
    const float* bnm = (const float*)d_in[5];
    const float* bnv = (const float*)d_in[6];
    const float* ppw = (const float*)d_in[7];
    const float* ppb = (const float*)d_in[8];
    const float* paw = (const float*)d_in[9];
    const float* pab = (const float*)d_in[10];
    const float* w1  = (const float*)d_in[11];
    const float* bu1 = (const float*)d_in[12];
    const float* ba1 = (const float*)d_in[13];
    const float* w2  = (const float*)d_in[14];
    const float* bu2 = (const float*)d_in[15];
    const float* ba2 = (const float*)d_in[16];
    const float* wcp = (const float*)d_in[17];
    const float* buc = (const float*)d_in[18];
    const float* bac = (const float*)d_in[19];
    float* out = (float*)d_out;

    float* ws    = (float*)d_ws;
    float* y     = ws;               // 64*16*16*64      = 1048576
    float* poseP = y + 1048576;      // 64*16*16*128     = 2097152
    float* aP    = poseP + 2097152;  // 64*16*16*8       = 131072
    float* pose1 = aP + 131072;      // 64*7*7*16*16     = 802816
    float* a1    = pose1 + 802816;   // 64*7*7*16        = 50176
    float* pose2 = a1 + 50176;       // 64*5*5*16*16     = 409600
    float* a2    = pose2 + 409600;   // 64*5*5*16        = 25600
    float* w1t   = a2 + 25600;       // 18432
    float* w2t   = w1t + 18432;      // 36864
    float* wct   = w2t + 36864;      // 2560
    float* wpt   = wct + 2560;       // 65*136 = 8840

    const int transw_blocks = (3616 * 16 + 65 * 136 + 255) / 256;   // 261
    hipLaunchKernelGGL(k_conv_transw, dim3(4096 + transw_blocks), dim3(256), 0, stream,
                       x, c1w, c1b, bng, bnb, bnm, bnv, y,
                       w1, w2, wcp, ppw, ppb, paw, pab, w1t, w2t, wct, wpt);
    hipLaunchKernelGGL(k_prim, dim3((16384 * 34 + 255) / 256), dim3(256), 0, stream,
                       y, wpt, poseP, aP);
    // stage 1: N=72, 3136 positions -> 3136 single-wave blocks (LDS ~4.9 KB)
    hipLaunchKernelGGL((k_caps_w1<72, 16, 3, 2, 16, 16, 8, 7, 7>), dim3(3136), dim3(64), 0, stream,
                       poseP, aP, w1t, bu1, ba1, pose1, a1);
    // stage 2: N=144, 1600 positions -> 1600 single-wave blocks (LDS ~9.8 KB)
    hipLaunchKernelGGL((k_caps_w1<144, 16, 3, 1, 7, 7, 16, 5, 5>), dim3(1600), dim3(64), 0, stream,
                       pose1, a1, w2t, bu2, ba2, pose2, a2);
    // class: N=400, C=10, coords, BLK=1024
    hipLaunchKernelGGL((k_caps_class<400, 10, 5, 5, 16, 1024>), dim3(64), dim3(1024), 0, stream,
                       pose2, a2, wct, buc, bac, out);
}